// Round 3
// baseline (119.355 us; speedup 1.0000x reference)
//
#include <hip/hip_runtime.h>

#define K_ITERS 20
#define MU_CONST 0.05f
#define BN 128
#define NB_PER_BLOCK 8
#define NBLOCKS 512

typedef const __attribute__((address_space(1))) void* gas_ptr;
typedef __attribute__((address_space(3))) void* las_ptr;

// Persistent: 512 blocks x 256 threads (2 blocks/CU, 8 waves/CU).
// Thread t owns row r=t>>1, cols [64h, 64h+64) -> 16 float4 of w in regs.
// Next batch's w prefetched into lds_w (async, swizzled source) during compute.
// y ping-pongs between two LDS buffers -> one barrier per iteration.
__global__ __launch_bounds__(256, 2) void nag_kernel(
    const float* __restrict__ w,
    const float* __restrict__ bvec,
    const float* __restrict__ s_ptr,
    float* __restrict__ out,
    int B)
{
    __shared__ __align__(16) float lds_w[BN * BN];   // 64 KiB staging
    __shared__ __align__(16) float y_lds[2][BN];     // ping-pong y

    const int t    = threadIdx.x;     // 0..255
    const int lane = t & 63;
    const int wv   = t >> 6;          // wave 0..3
    const int r    = t >> 1;          // row 0..127
    const int h    = t & 1;           // column half
    const int sw   = r & 7;           // read-side swizzle key

    const float s    = *s_ptr;
    const float sqms = sqrtf(MU_CONST * s);
    const float alpha = (1.0f - sqms) / (1.0f + sqms);
    const float ap1   = 1.0f + alpha;

    const int base = blockIdx.x * NB_PER_BLOCK;
    if (base >= B) return;
    const int nb = (B - base < NB_PER_BLOCK) ? (B - base) : NB_PER_BLOCK;

    // Async stage of one batch's 128x128 w into lds_w.
    // LDS dst linear (wave-uniform base + lane*16); XOR swizzle applied on the
    // per-lane GLOBAL source so the strided read-back is bank-conflict-free.
    auto stage = [&](int nbatch) {
        const float* wb = w + (size_t)nbatch * (BN * BN);
#pragma unroll
        for (int k = 0; k < 16; ++k) {
            const int inst = wv * 16 + k;            // 0..63, 1 KiB each
            const int rho  = inst * 2 + (lane >> 5); // row this lane feeds
            const int c4   = lane & 31;              // float4 col (linear LDS)
            const int G    = rho * 32 + (c4 ^ (rho & 7));
            const float* src = wb + (size_t)G * 4;
            float* dst = lds_w + inst * 256;         // wave-uniform LDS base
            __builtin_amdgcn_global_load_lds((gas_ptr)src, (las_ptr)dst, 16, 0, 0);
        }
    };

    float4 w4[16];
    const float4* lw4 = (const float4*)lds_w;

    // LDS (staged, swizzled) -> registers; also zero y[0] for the new batch.
    auto copy_regs = [&]() {
#pragma unroll
        for (int j = 0; j < 16; ++j)
            w4[j] = lw4[r * 32 + ((h * 16 + j) ^ sw)];
        if (t < BN) y_lds[0][t] = 0.0f;
    };

    // ---- prologue ----
    stage(base);
    asm volatile("s_waitcnt vmcnt(0)" ::: "memory");
    __builtin_amdgcn_sched_barrier(0);
    __builtin_amdgcn_s_barrier();
    asm volatile("" ::: "memory");
    copy_regs();
    asm volatile("s_waitcnt lgkmcnt(0)" ::: "memory");
    __builtin_amdgcn_sched_barrier(0);
    __builtin_amdgcn_s_barrier();
    asm volatile("" ::: "memory");

    for (int bi = 0; bi < nb; ++bi) {
        const int batch = base + bi;

        // issued before stage() so its waitcnt doesn't drain the prefetch
        const float b_r = bvec[(size_t)batch * BN + r];

        if (bi + 1 < nb) stage(batch + 1);   // overlaps the compute below

        float x = 0.0f, ys = 0.0f;

        for (int it = 0; it < K_ITERS; ++it) {
            const float4* y4 = (const float4*)(y_lds[it & 1]) + h * 16;
            float p0 = 0.f, p1 = 0.f, p2 = 0.f, p3 = 0.f;
#pragma unroll
            for (int j = 0; j < 4; ++j) {
                float4 a0 = w4[4*j+0], a1 = w4[4*j+1];
                float4 a2 = w4[4*j+2], a3 = w4[4*j+3];
                float4 v0 = y4[4*j+0], v1 = y4[4*j+1];
                float4 v2 = y4[4*j+2], v3 = y4[4*j+3];
                p0 += a0.x*v0.x; p0 += a0.y*v0.y; p0 += a0.z*v0.z; p0 += a0.w*v0.w;
                p1 += a1.x*v1.x; p1 += a1.y*v1.y; p1 += a1.z*v1.z; p1 += a1.w*v1.w;
                p2 += a2.x*v2.x; p2 += a2.y*v2.y; p2 += a2.z*v2.z; p2 += a2.w*v2.w;
                p3 += a3.x*v3.x; p3 += a3.y*v3.y; p3 += a3.z*v3.z; p3 += a3.w*v3.w;
            }
            const float pp = (p0 + p1) + (p2 + p3);
            const float d  = pp + __shfl_xor(pp, 1);
            const float xn = ys - s * (d - b_r);
            ys = ap1 * xn - alpha * x;
            x  = xn;

            if (it != K_ITERS - 1) {
                if (h == 0) y_lds[(it & 1) ^ 1][r] = ys;
                // raw barrier (must NOT drain vmcnt: prefetch stays in flight)
                asm volatile("s_waitcnt lgkmcnt(0)" ::: "memory");
                __builtin_amdgcn_sched_barrier(0);
                __builtin_amdgcn_s_barrier();
                asm volatile("" ::: "memory");
            }
        }

        // outputs: x then y, each B*BN flat; the lane pair holds row r's state
        {
            const size_t ob = (size_t)batch * BN;
            const size_t oy = (size_t)B * BN;
            if (h == 0) out[ob + r] = x;
            else        out[oy + ob + r] = ys;
        }

        // batch switch: drain prefetch ONCE, copy staged w to regs
        if (bi + 1 < nb) {
            asm volatile("s_waitcnt vmcnt(0)" ::: "memory");
            __builtin_amdgcn_sched_barrier(0);
            __builtin_amdgcn_s_barrier();          // staged tile visible
            asm volatile("" ::: "memory");
            copy_regs();
            asm volatile("s_waitcnt lgkmcnt(0)" ::: "memory");
            __builtin_amdgcn_sched_barrier(0);
            __builtin_amdgcn_s_barrier();          // copies done -> lds_w free
            asm volatile("" ::: "memory");
        }
    }
}

extern "C" void kernel_launch(void* const* d_in, const int* in_sizes, int n_in,
                              void* d_out, int out_size, void* d_ws, size_t ws_size,
                              hipStream_t stream) {
    const float* w = (const float*)d_in[0];
    const float* b = (const float*)d_in[1];
    const float* s = (const float*)d_in[2];
    float* out = (float*)d_out;
    const int B = in_sizes[1] / BN;    // 4096
    nag_kernel<<<dim3(NBLOCKS), dim3(256), 0, stream>>>(w, b, s, out, B);
}

// Round 4
// 77.626 us; speedup vs baseline: 1.5376x; 1.5376x over previous
//
#include <hip/hip_runtime.h>

#define K_ITERS 20
#define MU_CONST 0.05f
#define BN 128
#define NB 8            // batches per block (512 blocks * 8 = 4096)
#define NBLOCKS 512
#define YSTRIDE 24      // float stride between 16-float y slices (bank spread)

// DPP butterfly add step (pure VALU cross-lane; ctrl must be immediate).
template <int CTRL>
__device__ __forceinline__ float dpp_add(float v) {
    int x = __builtin_amdgcn_update_dpp(0, __float_as_int(v), CTRL, 0xF, 0xF, true);
    return v + __int_as_float(x);
}
// full sum over the 8 lanes sharing a row-quad (lane bits [2:0] = col-group g)
__device__ __forceinline__ float reduce8(float v) {
    v = dpp_add<0xB1>(v);   // quad_perm [1,0,3,2]  : xor 1
    v = dpp_add<0x4E>(v);   // quad_perm [2,3,0,1]  : xor 2
    v = dpp_add<0x141>(v);  // row_half_mirror      : folds the two quads of 8
    return v;
}

// 512 persistent blocks x 256 threads (2 blocks/CU, 8 waves/CU).
// Lane (wv,q,g): rows wv*32+q*4+{0..3}, cols g*16+{0..15} -> 16 float4 of w.
// y lives in LDS (slice-strided); next batch's w double-buffers in registers.
__global__ __launch_bounds__(256, 2) void nag_kernel(
    const float* __restrict__ w,
    const float* __restrict__ bvec,
    const float* __restrict__ s_ptr,
    float* __restrict__ out,
    int B)
{
    __shared__ __align__(16) float y_lds[2][8 * YSTRIDE];   // 2 x 768 B

    const int t  = threadIdx.x;       // 0..255
    const int wv = t >> 6;            // wave 0..3
    const int q  = (t >> 3) & 7;      // row-quad within wave
    const int g  = t & 7;             // col-group (16 cols)
    const int row0   = wv * 32 + q * 4;
    const int wslice = (row0 >> 4) * YSTRIDE + (q & 3) * 4;  // write offset
    const int rbase  = g * YSTRIDE;                          // read offset

    const float s     = *s_ptr;
    const float sqms  = sqrtf(MU_CONST * s);
    const float alpha = (1.0f - sqms) / (1.0f + sqms);
    const float ap1   = 1.0f + alpha;

    const int base = blockIdx.x * NB;

    float4 wa[4][4], wb[4][4];

    auto load_w = [&](float4 (&wr)[4][4], int nb_) {
        const float* wp = w + (size_t)nb_ * (BN * BN) + (size_t)row0 * BN + g * 16;
#pragma unroll
        for (int rho = 0; rho < 4; ++rho)
#pragma unroll
            for (int k = 0; k < 4; ++k)
                wr[rho][k] = *reinterpret_cast<const float4*>(wp + rho * BN + k * 4);
    };

    auto body = [&](float4 (&wc)[4][4], float4 (&wn)[4][4], int batch, bool pf) {
        // per-row b values (L1-served, 8-way redundant across g)
        const float* bb = bvec + (size_t)batch * BN + row0;
        float br[4];
#pragma unroll
        for (int rho = 0; rho < 4; ++rho) br[rho] = bb[rho];

        // closed-form step 1 (y0 = 0): x1 = s*b, y1 = (1+alpha)*x1
        float xs[4], ys[4];
#pragma unroll
        for (int rho = 0; rho < 4; ++rho) {
            xs[rho] = s * br[rho];
            ys[rho] = ap1 * xs[rho];
        }
        if (g == 0)
            *reinterpret_cast<float4*>(&y_lds[0][wslice]) =
                make_float4(ys[0], ys[1], ys[2], ys[3]);

        // issue next batch's w loads now; they ride through the raw barriers
        if (pf) load_w(wn, batch + 1);
        __builtin_amdgcn_sched_barrier(0);

        asm volatile("s_waitcnt lgkmcnt(0)" ::: "memory");
        __builtin_amdgcn_sched_barrier(0);
        __builtin_amdgcn_s_barrier();          // y1 visible
        asm volatile("" ::: "memory");

#pragma unroll 2
        for (int it = 1; it < K_ITERS; ++it) {
            const float* yb = &y_lds[(it + 1) & 1][rbase];
            float4 yv[4];
#pragma unroll
            for (int k = 0; k < 4; ++k)
                yv[k] = *reinterpret_cast<const float4*>(yb + k * 4);

#pragma unroll
            for (int rho = 0; rho < 4; ++rho) {
                float p = wc[rho][0].x * yv[0].x;
                p = fmaf(wc[rho][0].y, yv[0].y, p);
                p = fmaf(wc[rho][0].z, yv[0].z, p);
                p = fmaf(wc[rho][0].w, yv[0].w, p);
                p = fmaf(wc[rho][1].x, yv[1].x, p);
                p = fmaf(wc[rho][1].y, yv[1].y, p);
                p = fmaf(wc[rho][1].z, yv[1].z, p);
                p = fmaf(wc[rho][1].w, yv[1].w, p);
                p = fmaf(wc[rho][2].x, yv[2].x, p);
                p = fmaf(wc[rho][2].y, yv[2].y, p);
                p = fmaf(wc[rho][2].z, yv[2].z, p);
                p = fmaf(wc[rho][2].w, yv[2].w, p);
                p = fmaf(wc[rho][3].x, yv[3].x, p);
                p = fmaf(wc[rho][3].y, yv[3].y, p);
                p = fmaf(wc[rho][3].z, yv[3].z, p);
                p = fmaf(wc[rho][3].w, yv[3].w, p);
                const float d  = reduce8(p);           // full 128-col dot
                const float xn = fmaf(-s, d - br[rho], ys[rho]);
                ys[rho] = fmaf(ap1, xn, -(alpha * xs[rho]));
                xs[rho] = xn;
            }

            if (it != K_ITERS - 1 && g == 0)
                *reinterpret_cast<float4*>(&y_lds[it & 1][wslice]) =
                    make_float4(ys[0], ys[1], ys[2], ys[3]);

            // raw barrier: drains LDS only, prefetch vmcnt stays in flight
            asm volatile("s_waitcnt lgkmcnt(0)" ::: "memory");
            __builtin_amdgcn_sched_barrier(0);
            __builtin_amdgcn_s_barrier();
            asm volatile("" ::: "memory");
        }

        // outputs: x then y, each B*BN flat; rows row0..row0+3 are contiguous
        const size_t ob = (size_t)batch * BN + row0;
        if (g == 0)
            *reinterpret_cast<float4*>(out + ob) =
                make_float4(xs[0], xs[1], xs[2], xs[3]);
        else if (g == 1)
            *reinterpret_cast<float4*>(out + (size_t)B * BN + ob) =
                make_float4(ys[0], ys[1], ys[2], ys[3]);
    };

    load_w(wa, base);
#pragma unroll 1
    for (int i2 = 0; i2 < NB / 2; ++i2) {
        body(wa, wb, base + 2 * i2,     true);
        body(wb, wa, base + 2 * i2 + 1, (2 * i2 + 2) < NB);
    }
}

extern "C" void kernel_launch(void* const* d_in, const int* in_sizes, int n_in,
                              void* d_out, int out_size, void* d_ws, size_t ws_size,
                              hipStream_t stream) {
    const float* w = (const float*)d_in[0];
    const float* b = (const float*)d_in[1];
    const float* s = (const float*)d_in[2];
    float* out = (float*)d_out;
    const int B = in_sizes[1] / BN;    // 4096
    nag_kernel<<<dim3(NBLOCKS), dim3(256), 0, stream>>>(w, b, s, out, B);
}

// Round 5
// 74.991 us; speedup vs baseline: 1.5916x; 1.0351x over previous
//
#include <hip/hip_runtime.h>

#define K_ITERS 20
#define MU_CONST 0.05f
#define BN 128
#define NB 8            // batches per block (512 blocks * 8 = 4096)
#define NBLOCKS 512
#define YSTRIDE 24      // float stride between 16-float y slices (bank spread)

typedef float v4f __attribute__((ext_vector_type(4)));
typedef __attribute__((address_space(1))) const v4f gc4;   // global const float4
typedef __attribute__((address_space(1))) v4f g4;          // global float4

// DPP butterfly add step (pure VALU cross-lane; ctrl must be immediate).
template <int CTRL>
__device__ __forceinline__ float dpp_add(float v) {
    int x = __builtin_amdgcn_update_dpp(0, __float_as_int(v), CTRL, 0xF, 0xF, true);
    return v + __int_as_float(x);
}
// sum over the 8 lanes sharing a row-quad (lane bits [2:0] = col-group g)
__device__ __forceinline__ float reduce8(float v) {
    v = dpp_add<0xB1>(v);   // quad_perm xor1
    v = dpp_add<0x4E>(v);   // quad_perm xor2
    v = dpp_add<0x141>(v);  // row_half_mirror (other quad holds its quad-sum)
    return v;
}

// 512 persistent blocks x 256 threads (2 blocks/CU, 8 waves/CU).
// Lane (wv,q,g): rows wv*32+q*4+{0..3}, cols g*16+{0..15} -> 16 float4 of w.
// w and b double-buffer in registers; next batch's loads issue at body start
// and stay in flight (vmcnt) through the 19 raw-barrier iterations.
__global__ __launch_bounds__(256, 2) void nag_kernel(
    const float* __restrict__ w,
    const float* __restrict__ bvec,
    const float* __restrict__ s_ptr,
    float* __restrict__ out,
    int B)
{
    __shared__ __align__(16) float y_lds[2][8 * YSTRIDE];   // 2 x 768 B

    const int t  = threadIdx.x;       // 0..255
    const int wv = t >> 6;            // wave 0..3
    const int q  = (t >> 3) & 7;      // row-quad within wave
    const int g  = t & 7;             // col-group (16 cols)
    const int row0   = wv * 32 + q * 4;
    const int wslice = (row0 >> 4) * YSTRIDE + (q & 3) * 4;  // y write offset
    const int rbase  = g * YSTRIDE;                          // y read offset

    const float s     = *s_ptr;
    const float sqms  = sqrtf(MU_CONST * s);
    const float alpha = (1.0f - sqms) / (1.0f + sqms);
    const float ap1   = 1.0f + alpha;

    const int base = blockIdx.x * NB;

    v4f wa[4][4], wb[4][4];
    v4f ba, bbuf;

    // explicit AS(1): guaranteed global_load (vmcnt-only, never lgkm)
    auto load_w = [&](v4f (&wr)[4][4], int nb_) {
        const gc4* wp = (const gc4*)(w + (size_t)nb_ * (BN * BN)
                                       + (size_t)row0 * BN + g * 16);
#pragma unroll
        for (int rho = 0; rho < 4; ++rho)
#pragma unroll
            for (int k = 0; k < 4; ++k)
                wr[rho][k] = wp[rho * 32 + k];
    };
    auto load_b = [&](v4f& br, int nb_) {
        br = *(const gc4*)(bvec + (size_t)nb_ * BN + row0);
    };

    auto body = [&](v4f (&wc)[4][4], v4f (&wn)[4][4],
                    v4f& brc, v4f& brn, int batch, bool pf) {
        const float br0 = brc.x, br1 = brc.y, br2 = brc.z, br3 = brc.w;

        // closed-form step 1 (y0 = 0): x1 = s*b, y1 = (1+alpha)*x1
        float xs[4], ys[4];
        xs[0] = s * br0; xs[1] = s * br1; xs[2] = s * br2; xs[3] = s * br3;
#pragma unroll
        for (int rho = 0; rho < 4; ++rho) ys[rho] = ap1 * xs[rho];
        if (g == 0)
            *reinterpret_cast<v4f*>(&y_lds[0][wslice]) =
                (v4f){ys[0], ys[1], ys[2], ys[3]};

        // issue next batch's loads now; they ride through the raw barriers
        if (pf) { load_w(wn, batch + 1); load_b(brn, batch + 1); }

        __builtin_amdgcn_sched_barrier(0);
        asm volatile("s_waitcnt lgkmcnt(0)");      // y1 write done (no memory clobber!)
        __builtin_amdgcn_s_barrier();
        __builtin_amdgcn_sched_barrier(0);

#pragma unroll 2
        for (int it = 1; it < K_ITERS; ++it) {
            const float* yb = &y_lds[(it + 1) & 1][rbase];
            v4f yv[4];
#pragma unroll
            for (int k = 0; k < 4; ++k)
                yv[k] = *reinterpret_cast<const v4f*>(yb + k * 4);

            float br_[4] = {br0, br1, br2, br3};
#pragma unroll
            for (int rho = 0; rho < 4; ++rho) {
                float p = wc[rho][0].x * yv[0].x;
                p = fmaf(wc[rho][0].y, yv[0].y, p);
                p = fmaf(wc[rho][0].z, yv[0].z, p);
                p = fmaf(wc[rho][0].w, yv[0].w, p);
                p = fmaf(wc[rho][1].x, yv[1].x, p);
                p = fmaf(wc[rho][1].y, yv[1].y, p);
                p = fmaf(wc[rho][1].z, yv[1].z, p);
                p = fmaf(wc[rho][1].w, yv[1].w, p);
                p = fmaf(wc[rho][2].x, yv[2].x, p);
                p = fmaf(wc[rho][2].y, yv[2].y, p);
                p = fmaf(wc[rho][2].z, yv[2].z, p);
                p = fmaf(wc[rho][2].w, yv[2].w, p);
                p = fmaf(wc[rho][3].x, yv[3].x, p);
                p = fmaf(wc[rho][3].y, yv[3].y, p);
                p = fmaf(wc[rho][3].z, yv[3].z, p);
                p = fmaf(wc[rho][3].w, yv[3].w, p);
                const float d  = reduce8(p);           // full 128-col dot
                const float xn = fmaf(-s, d - br_[rho], ys[rho]);
                ys[rho] = fmaf(ap1, xn, -(alpha * xs[rho]));
                xs[rho] = xn;
            }

            if (it != K_ITERS - 1 && g == 0)
                *reinterpret_cast<v4f*>(&y_lds[it & 1][wslice]) =
                    (v4f){ys[0], ys[1], ys[2], ys[3]};

            // raw barrier idiom (template-verified): pins order, drains LDS
            // only — prefetch vmcnt stays in flight.
            __builtin_amdgcn_sched_barrier(0);
            asm volatile("s_waitcnt lgkmcnt(0)");
            __builtin_amdgcn_s_barrier();
            __builtin_amdgcn_sched_barrier(0);
        }

        // outputs: x then y, each B*BN flat; rows row0..row0+3 contiguous
        const size_t ob = (size_t)batch * BN + row0;
        if (g == 0)
            *(g4*)(out + ob) = (v4f){xs[0], xs[1], xs[2], xs[3]};
        else if (g == 1)
            *(g4*)(out + (size_t)B * BN + ob) = (v4f){ys[0], ys[1], ys[2], ys[3]};
    };

    load_w(wa, base);
    load_b(ba, base);
#pragma unroll 1
    for (int i2 = 0; i2 < NB / 2; ++i2) {
        body(wa, wb, ba, bbuf, base + 2 * i2, true);
        body(wb, wa, bbuf, ba, base + 2 * i2 + 1, (2 * i2 + 2) < NB);
    }
}

extern "C" void kernel_launch(void* const* d_in, const int* in_sizes, int n_in,
                              void* d_out, int out_size, void* d_ws, size_t ws_size,
                              hipStream_t stream) {
    const float* w = (const float*)d_in[0];
    const float* b = (const float*)d_in[1];
    const float* s = (const float*)d_in[2];
    float* out = (float*)d_out;
    const int B = in_sizes[1] / BN;    // 4096
    nag_kernel<<<dim3(NBLOCKS), dim3(256), 0, stream>>>(w, b, s, out, B);
}